// Round 2
// baseline (215.017 us; speedup 1.0000x reference)
//
#include <hip/hip_runtime.h>

// Problem constants (fixed by reference setup_inputs): B=32, C=3, H=W=512.
#define HW_PLANE (512 * 512)          // 2^18
#define TOTAL_PIX (32 * HW_PLANE)     // 2^23
#define TOTAL_QUADS (TOTAL_PIX / 4)   // 2^21
#define N_ELEMS (32 * 3 * HW_PLANE)   // B*C*H*W

__global__ void init_out_kernel(float* out) {
    if (threadIdx.x == 0 && blockIdx.x == 0) out[0] = 0.0f;
}

__global__ __launch_bounds__(256) void mae_bbox_kernel(
    const float* __restrict__ x, const float* __restrict__ y,
    const int* __restrict__ bbox, float* __restrict__ out) {

    const float inv_n = 1.0f / (float)N_ELEMS;
    float acc = 0.0f;

    const int stride = gridDim.x * blockDim.x;
    for (int q = blockIdx.x * blockDim.x + threadIdx.x; q < TOTAL_QUADS; q += stride) {
        const int p   = q << 2;              // first pixel index of the quad
        const int b   = p >> 18;             // / (512*512)
        const int rem = p & (HW_PLANE - 1);
        const int h   = rem >> 9;            // / 512
        const int w0  = rem & 511;           // % 512

        // bbox[b]: 4 points, layout (x,y) pairs -> 8 ints. Tiny, L1-cached.
        const int* bb = bbox + (b << 3);
        const int xmin = min(min(bb[0], bb[2]), min(bb[4], bb[6]));
        const int xmax = max(max(bb[0], bb[2]), max(bb[4], bb[6]));
        const int ymin = min(min(bb[1], bb[3]), min(bb[5], bb[7]));
        const int ymax = max(max(bb[1], bb[3]), max(bb[5], bb[7]));

        // border band only active when bbox+margin strictly interior
        const bool cond = (xmin > 5) && (xmax < 507) && (ymin > 5) && (ymax < 507);

        const bool inrow = (h >= ymin) && (h < ymax);
        // vertical ramp: exact nested-where chain of the reference
        const int fy = inrow ? 5
                     : ((h >= ymin - 5 && h < ymin) ? (h - ymin + 6)
                     : ((h >= ymax && h < ymax + 5) ? (5 - (h - ymax)) : 0));

        float wq[4];
#pragma unroll
        for (int j = 0; j < 4; ++j) {
            const int wx = w0 + j;
            const bool incol = (wx >= xmin) && (wx < xmax);
            const int fx = incol ? 5
                         : ((wx >= xmin - 5 && wx < xmin) ? (wx - xmin + 6)
                         : ((wx >= xmax && wx < xmax + 5) ? (5 - (wx - xmax)) : 0));
            const bool inside = inrow && incol;
            float wv = inside ? 100.0f : 1.0f;
            if (cond && (fy > 0) && (fx > 0) && !inside)
                wv = (float)min(fy, fx) * 20.0f;   // min(fy,fx)/m * ALPHA, m=5, ALPHA=100
            wq[j] = wv;
        }

        const size_t base = (size_t)(b * 3) * HW_PLANE + (size_t)rem;
#pragma unroll
        for (int c = 0; c < 3; ++c) {
            const float4 xv = *reinterpret_cast<const float4*>(x + base + (size_t)c * HW_PLANE);
            const float4 yv = *reinterpret_cast<const float4*>(y + base + (size_t)c * HW_PLANE);
            acc = fmaf(fabsf(xv.x - yv.x), wq[0], acc);
            acc = fmaf(fabsf(xv.y - yv.y), wq[1], acc);
            acc = fmaf(fabsf(xv.z - yv.z), wq[2], acc);
            acc = fmaf(fabsf(xv.w - yv.w), wq[3], acc);
        }
    }

    // wave-64 shuffle reduce
#pragma unroll
    for (int off = 32; off > 0; off >>= 1) acc += __shfl_down(acc, off, 64);

    __shared__ float sred[4];
    const int lane = threadIdx.x & 63;
    const int wid  = threadIdx.x >> 6;
    if (lane == 0) sred[wid] = acc;
    __syncthreads();
    if (threadIdx.x == 0) {
        const float s = sred[0] + sred[1] + sred[2] + sred[3];
        atomicAdd(out, s * inv_n);   // pre-normalized partial: small magnitude, low atomic rounding error
    }
}

extern "C" void kernel_launch(void* const* d_in, const int* in_sizes, int n_in,
                              void* d_out, int out_size, void* d_ws, size_t ws_size,
                              hipStream_t stream) {
    const float* x    = (const float*)d_in[0];
    const float* y    = (const float*)d_in[1];
    const int*   bbox = (const int*)d_in[2];
    float* out = (float*)d_out;

    // d_out is re-poisoned (0xAA) before every timed launch: zero it first.
    init_out_kernel<<<1, 64, 0, stream>>>(out);

    // 2048 blocks x 256 threads; each thread grid-strides ~4 quads.
    mae_bbox_kernel<<<2048, 256, 0, stream>>>(x, y, bbox, out);
}

// Round 3
// 213.691 us; speedup vs baseline: 1.0062x; 1.0062x over previous
//
#include <hip/hip_runtime.h>

// Problem constants (fixed by reference setup_inputs): B=32, C=3, H=W=512.
#define HW_PLANE (512 * 512)                 // 2^18 pixels per plane
#define QUADS_PER_BATCH (HW_PLANE / 4)       // 65536
#define BLOCKS_PER_BATCH 64
#define QUADS_PER_BLOCK (QUADS_PER_BATCH / BLOCKS_PER_BATCH)  // 1024
#define NBLOCKS (32 * BLOCKS_PER_BATCH)      // 2048
#define N_ELEMS (32 * 3 * HW_PLANE)          // B*C*H*W

// Stage 1: each block handles 1024 consecutive quads of ONE batch image.
// b = blockIdx>>6 is block-uniform -> bbox goes through scalar loads, min/max
// on SALU once per block (was: 8 per-lane VGPR loads per loop iteration).
// Block partial -> d_ws[blockIdx.x]; NO same-address atomics (round-2 theory:
// 2048 serialized cross-XCD atomics to one line were the ~50us tail).
__global__ __launch_bounds__(256) void mae_bbox_kernel(
    const float* __restrict__ x, const float* __restrict__ y,
    const int* __restrict__ bbox, float* __restrict__ ws) {

    const int b     = blockIdx.x >> 6;   // batch index, uniform per block
    const int chunk = blockIdx.x & 63;   // which 1024-quad chunk of the plane

    const int* bb = bbox + (b << 3);     // uniform address -> s_load
    const int xmin = min(min(bb[0], bb[2]), min(bb[4], bb[6]));
    const int xmax = max(max(bb[0], bb[2]), max(bb[4], bb[6]));
    const int ymin = min(min(bb[1], bb[3]), min(bb[5], bb[7]));
    const int ymax = max(max(bb[1], bb[3]), max(bb[5], bb[7]));
    // border band only active when bbox+margin strictly interior
    const bool cond = (xmin > 5) && (xmax < 507) && (ymin > 5) && (ymax < 507);

    const size_t bbase = (size_t)(b * 3) * HW_PLANE;
    float acc = 0.0f;

#pragma unroll
    for (int it = 0; it < 4; ++it) {
        const int qb = chunk * QUADS_PER_BLOCK + it * 256 + (int)threadIdx.x;
        const int p  = qb << 2;          // pixel index within the plane
        const int h  = p >> 9;           // row
        const int w0 = p & 511;          // col of first pixel in quad

        const bool inrow = (h >= ymin) && (h < ymax);
        // vertical ramp: exact nested-where chain of the reference
        const int fy = inrow ? 5
                     : ((h >= ymin - 5 && h < ymin) ? (h - ymin + 6)
                     : ((h >= ymax && h < ymax + 5) ? (5 - (h - ymax)) : 0));

        float wq[4];
#pragma unroll
        for (int j = 0; j < 4; ++j) {
            const int wx = w0 + j;
            const bool incol = (wx >= xmin) && (wx < xmax);
            const int fx = incol ? 5
                         : ((wx >= xmin - 5 && wx < xmin) ? (wx - xmin + 6)
                         : ((wx >= xmax && wx < xmax + 5) ? (5 - (wx - xmax)) : 0));
            const bool inside = inrow && incol;
            float wv = inside ? 100.0f : 1.0f;
            if (cond && (fy > 0) && (fx > 0) && !inside)
                wv = (float)min(fy, fx) * 20.0f;   // min(fy,fx)/m * ALPHA, m=5, ALPHA=100
            wq[j] = wv;
        }

        const size_t base = bbase + (size_t)p;
#pragma unroll
        for (int c = 0; c < 3; ++c) {
            const float4 xv = *reinterpret_cast<const float4*>(x + base + (size_t)c * HW_PLANE);
            const float4 yv = *reinterpret_cast<const float4*>(y + base + (size_t)c * HW_PLANE);
            acc = fmaf(fabsf(xv.x - yv.x), wq[0], acc);
            acc = fmaf(fabsf(xv.y - yv.y), wq[1], acc);
            acc = fmaf(fabsf(xv.z - yv.z), wq[2], acc);
            acc = fmaf(fabsf(xv.w - yv.w), wq[3], acc);
        }
    }

    // wave-64 shuffle reduce
#pragma unroll
    for (int off = 32; off > 0; off >>= 1) acc += __shfl_down(acc, off, 64);

    __shared__ float sred[4];
    const int lane = threadIdx.x & 63;
    const int wid  = threadIdx.x >> 6;
    if (lane == 0) sred[wid] = acc;
    __syncthreads();
    if (threadIdx.x == 0)
        ws[blockIdx.x] = sred[0] + sred[1] + sred[2] + sred[3];
}

// Stage 2: one block sums the 2048 partials and writes the mean.
__global__ __launch_bounds__(256) void finalize_kernel(
    const float* __restrict__ ws, float* __restrict__ out) {
    float acc = 0.0f;
#pragma unroll
    for (int i = 0; i < NBLOCKS / 256; ++i)
        acc += ws[i * 256 + threadIdx.x];

#pragma unroll
    for (int off = 32; off > 0; off >>= 1) acc += __shfl_down(acc, off, 64);

    __shared__ float sred[4];
    const int lane = threadIdx.x & 63;
    const int wid  = threadIdx.x >> 6;
    if (lane == 0) sred[wid] = acc;
    __syncthreads();
    if (threadIdx.x == 0)
        out[0] = (sred[0] + sred[1] + sred[2] + sred[3]) * (1.0f / (float)N_ELEMS);
}

extern "C" void kernel_launch(void* const* d_in, const int* in_sizes, int n_in,
                              void* d_out, int out_size, void* d_ws, size_t ws_size,
                              hipStream_t stream) {
    const float* x    = (const float*)d_in[0];
    const float* y    = (const float*)d_in[1];
    const int*   bbox = (const int*)d_in[2];
    float* out = (float*)d_out;
    float* ws  = (float*)d_ws;   // needs NBLOCKS*4 = 8 KB of scratch

    mae_bbox_kernel<<<NBLOCKS, 256, 0, stream>>>(x, y, bbox, ws);
    finalize_kernel<<<1, 256, 0, stream>>>(ws, out);
}